// Round 6
// baseline (125.327 us; speedup 1.0000x reference)
//
#include <hip/hip_runtime.h>
#include <math.h>

#define HH 1080
#define WW 1920
#define RAD 5
#define TX 32
#define TY 32
#define RPT 4
#define BDY 8
#define LR (TY + 2*RAD)   // 42
#define LC (TX + 2*RAD)   // 42

__device__ __forceinline__ float fast_rcp(float x) {
#if __has_builtin(__builtin_amdgcn_rcpf)
    return __builtin_amdgcn_rcpf(x);
#else
    return 1.0f / x;
#endif
}
__device__ __forceinline__ float fast_rsq(float x) {
#if __has_builtin(__builtin_amdgcn_rsqf)
    return __builtin_amdgcn_rsqf(x);
#else
    return rsqrtf(x);
#endif
}
__device__ __forceinline__ float fast_exp2(float x) {
#if __has_builtin(__builtin_amdgcn_exp2f)
    return __builtin_amdgcn_exp2f(x);
#else
    return exp2f(x);
#endif
}

// Weight: w = exp(-d2/8) * clip(dot,0,1)^128 * exp(-|tz-z| / max(dz*sqrt(d2), 1e-4))
// All three factors in ONE exp2:
//   w = exp2( -c*d2  +  128*log2e*LN(dot)  -  |tz-z| * min(rdz*rsqrt(d2), 1e4*log2e) )
//   c = log2e/8, rdz = log2e * rcp(dz), 1/max(a,eps) == min(1/a,1/eps).
// LN(dot) = cubic ln approx: t = min(dot-1,0); L = t*(1 + t*(-1/2 + t/3)).
//   For taps with w_n >= 0.01 (dot>=0.9646) poly err <= 4e-7 -> weight err 0.007%.
//   For small dot, L stays monotone-negative (t=-1 -> exponent -338 -> w=0), so
//   clip-at-0 and the zero-padded-halo mask (normals=0 -> dot=0 -> w=0) still hold.
// Per-(row,o,k) {cx,tm} register tables (R4 lesson: registers, not LDS); the rsqrt
// part rolls across rows (RS0..RS3 window): row r needs dy in {r-5..r-8}, three of
// which were computed last row -> only 6 fresh rsq per row.
// Center tap: rsqrt(0)=inf -> tm clamps to BIG; zd==0 -> fma(-0,BIG,e)=e; dot==1 -> w=1.
// (Fusion numerics validated R2-R5: absmax 3.9e-3 vs threshold 2e-2.)

__global__ __launch_bounds__(TX*BDY, 3)
void denoise_kernel(const float* __restrict__ in, float* __restrict__ out) {
    __shared__ float4 sA[LR][LC];   // c0,c1,c2,n0   28224 B
    __shared__ float2 sN[LR][LC];   // n1,n2         14112 B
    __shared__ float  sZ[LR][LC];   // z              7056 B -> 49392 B -> 3 blocks/CU

    const int tx = threadIdx.x;
    const int ty = threadIdx.y;
    const int tid = ty * TX + tx;
    const int x0 = blockIdx.x * TX;
    const int y0 = blockIdx.y * TY;

    // ---- stage tile + halo, normalizing normals on the fly ----
    #pragma unroll
    for (int i = 0; i < (LR * LC + TX * BDY - 1) / (TX * BDY); ++i) {
        int idx = tid + i * (TX * BDY);
        if (idx < LR * LC) {
            int r = idx / LC, c = idx % LC;
            int gx = x0 + c - RAD;
            int gy = y0 + r - RAD;
            float4 a = make_float4(0.f, 0.f, 0.f, 0.f);
            float4 b = make_float4(0.f, 0.f, 0.f, 0.f);
            if ((unsigned)gx < (unsigned)WW && (unsigned)gy < (unsigned)HH) {
                const float4* p = reinterpret_cast<const float4*>(in + ((size_t)gy * WW + gx) * 8);
                a = p[0];
                b = p[1];
            }
            float nn = a.w * a.w + b.x * b.x + b.y * b.y;
            float s = fast_rsq(fmaxf(nn, 1e-20f));
            sA[r][c] = make_float4(a.x, a.y, a.z, a.w * s);
            sN[r][c] = make_float2(b.x * s, b.y * s);
            sZ[r][c] = b.z;
        }
    }
    __syncthreads();

    // ---- per-thread centers: 4 vertically adjacent outputs ----
    float cn0[RPT], cn1[RPT], cn2[RPT], cz[RPT], rdz[RPT];
    #pragma unroll
    for (int o = 0; o < RPT; ++o) {
        int rr = ty * RPT + RAD + o, cc = tx + RAD;
        float4 A = sA[rr][cc];
        float2 N = sN[rr][cc];
        cn0[o] = A.w; cn1[o] = N.x; cn2[o] = N.y; cz[o] = sZ[rr][cc];
        int gy = y0 + ty * RPT + o;
        float dzv = 1.0f;
        if (gy < HH) dzv = in[(((size_t)gy * WW) + (x0 + tx)) * 8 + 7];
        rdz[o] = 1.4426950408889634f * fast_rcp(dzv);   // log2e folded in
    }

    float accx[RPT] = {0.f, 0.f, 0.f, 0.f};
    float accy[RPT] = {0.f, 0.f, 0.f, 0.f};
    float accz[RPT] = {0.f, 0.f, 0.f, 0.f};
    float accw[RPT] = {0.f, 0.f, 0.f, 0.f};

    // ---- rolling rsqrt window: RSj[k] = rsqrt(dy_j^2 + k^2), dy_j = r-RAD-j ----
    // Pre-loop state so that after the rotation at r=0: RS1<-dy=-6, RS2<-dy=-7, RS3<-dy=-8.
    float RS0[RAD + 1], RS1[RAD + 1], RS2[RAD + 1], RS3[RAD + 1];
    #pragma unroll
    for (int k = 0; k <= RAD; ++k) {
        RS0[k] = fast_rsq((float)(36 + k * k));   // dy=-6
        RS1[k] = fast_rsq((float)(49 + k * k));   // dy=-7
        RS2[k] = fast_rsq((float)(64 + k * k));   // dy=-8
        RS3[k] = 0.f;                             // rotated out immediately
    }

    // ROW_BODY(CHECK): one tap-row. Rotates the RS window, computes 6 fresh rsq,
    // builds per-(o,k) {cx,tm} register tables, then runs the 11x4 unrolled bodies
    // with compile-time k = |dx-RAD|. CHECK=false -> branch-free steady rows.
    #define ROW_BODY(CHECK)                                                          \
    {                                                                                \
        _Pragma("unroll")                                                            \
        for (int k = 0; k <= RAD; ++k) {                                             \
            RS3[k] = RS2[k]; RS2[k] = RS1[k]; RS1[k] = RS0[k];                       \
        }                                                                            \
        {                                                                            \
            int dy0 = r - RAD;                                                       \
            float dy0sq = (float)(dy0 * dy0);                                        \
            _Pragma("unroll")                                                        \
            for (int k = 0; k <= RAD; ++k)                                           \
                RS0[k] = fast_rsq(dy0sq + (float)(k * k));                           \
        }                                                                            \
        float tmv[RPT][RAD + 1], cxv[RPT][RAD + 1];                                  \
        bool  val[RPT];                                                              \
        _Pragma("unroll")                                                            \
        for (int o = 0; o < RPT; ++o) {                                              \
            int dy = r - RAD - o;                                                    \
            val[o] = (dy >= -RAD) && (dy <= RAD);                                    \
            float bneg = (float)(dy * dy) * -0.18033688011112042f;                   \
            const float* RSo = (o == 0) ? RS0 : (o == 1) ? RS1 : (o == 2) ? RS2 : RS3; \
            _Pragma("unroll")                                                        \
            for (int k = 0; k <= RAD; ++k) {                                         \
                cxv[o][k] = bneg + (float)(k * k) * -0.18033688011112042f;           \
                tmv[o][k] = fminf(rdz[o] * RSo[k], 14426.950408889634f);             \
            }                                                                        \
        }                                                                            \
        _Pragma("unroll")                                                            \
        for (int dx = 0; dx < 2 * RAD + 1; ++dx) {                                   \
            float4 A  = sA[ty * RPT + r][tx + dx];                                   \
            float2 N  = sN[ty * RPT + r][tx + dx];                                   \
            float  tz = sZ[ty * RPT + r][tx + dx];                                   \
            const int k = (dx < RAD) ? (RAD - dx) : (dx - RAD);                      \
            _Pragma("unroll")                                                        \
            for (int o = 0; o < RPT; ++o) {                                          \
                if (!CHECK || val[o]) {                                              \
                    float dot = fmaf(A.w, cn0[o], fmaf(N.x, cn1[o], N.y * cn2[o]));  \
                    float t   = fminf(dot - 1.0f, 0.0f);                             \
                    float p   = fmaf(t, 0.3333333333333333f, -0.5f);                 \
                    float q   = fmaf(t, p, 1.0f);                                    \
                    float L   = t * q;                                               \
                    float zd  = tz - cz[o];                                          \
                    float e2a = fmaf(-fabsf(zd), tmv[o][k], cxv[o][k]);              \
                    float e2  = fmaf(L, 184.66496523378733f, e2a);                   \
                    float w   = fast_exp2(e2);                                       \
                    accx[o] = fmaf(A.x, w, accx[o]);                                 \
                    accy[o] = fmaf(A.y, w, accy[o]);                                 \
                    accz[o] = fmaf(A.z, w, accz[o]);                                 \
                    accw[o] += w;                                                    \
                }                                                                    \
            }                                                                        \
        }                                                                            \
    }

    // ---- boundary rows (some o invalid) ----
    #pragma unroll 1
    for (int r = 0; r < RPT - 1; ++r) ROW_BODY(true)
    // ---- steady rows r in [3,10]: all 4 outputs valid, branch-free ----
    #pragma unroll 1
    for (int r = RPT - 1; r <= 2 * RAD; ++r) ROW_BODY(false)
    // ---- boundary rows ----
    #pragma unroll 1
    for (int r = 2 * RAD + 1; r < 2 * RAD + RPT; ++r) ROW_BODY(true)

    #undef ROW_BODY

    // ---- epilogue ----
    const int xo = x0 + tx;
    #pragma unroll
    for (int o = 0; o < RPT; ++o) {
        int y = y0 + ty * RPT + o;
        if (y < HH) {
            float inv = fast_rcp(accw[o]);
            size_t base = ((size_t)y * WW + xo) * 3;
            out[base + 0] = accx[o] * inv;
            out[base + 1] = accy[o] * inv;
            out[base + 2] = accz[o] * inv;
        }
    }
}

extern "C" void kernel_launch(void* const* d_in, const int* in_sizes, int n_in,
                              void* d_out, int out_size, void* d_ws, size_t ws_size,
                              hipStream_t stream) {
    const float* in = (const float*)d_in[0];
    float* out = (float*)d_out;
    dim3 grid((WW + TX - 1) / TX, (HH + TY - 1) / TY);   // 60 x 34
    dim3 block(TX, BDY);                                  // 256 threads
    hipLaunchKernelGGL(denoise_kernel, grid, block, 0, stream, in, out);
}

// Round 7
// 112.521 us; speedup vs baseline: 1.1138x; 1.1138x over previous
//
#include <hip/hip_runtime.h>
#include <math.h>

#define HH 1080
#define WW 1920
#define RAD 5
#define TX 32
#define TY 32
#define RPT 4
#define BDY 8
#define LR (TY + 2*RAD)   // 42
#define LC (TX + 2*RAD)   // 42

__device__ __forceinline__ float fast_rcp(float x) {
#if __has_builtin(__builtin_amdgcn_rcpf)
    return __builtin_amdgcn_rcpf(x);
#else
    return 1.0f / x;
#endif
}
__device__ __forceinline__ float fast_rsq(float x) {
#if __has_builtin(__builtin_amdgcn_rsqf)
    return __builtin_amdgcn_rsqf(x);
#else
    return rsqrtf(x);
#endif
}
__device__ __forceinline__ float fast_exp2(float x) {
#if __has_builtin(__builtin_amdgcn_exp2f)
    return __builtin_amdgcn_exp2f(x);
#else
    return exp2f(x);
#endif
}

// Weight: w = exp(-d2/8) * clip(dot,0,1)^128 * exp(-|tz-z| / max(dz*sqrt(d2), 1e-4))
// One exp2 with a fused quadratic for the normal term:
//   w = exp2( cx[d2] - |tz-z|*tm[d2] + t*(C - (C/2)*t) ),  t = dot-1, C = 128*log2e
//   (ln(1+t) ~= t - t^2/2; t*u and the final add fuse into ONE fma: e2 = fma(t, u, e2a).
//    err <= |t|^3/3 -> 0.19% weight err at w_n=0.01; monotone (1-t>0); t=-1 (clip/halo
//    mask) -> 2^-277 -> 0 exactly, reproducing the reference's clip-at-0 and t_m mask.
//    dot>1 only by ~ulp -> w~1.00003 vs reference clip at 1: negligible.)
//   cx[d2] = -d2*log2e/8;  tm[d2] = min(rdz*rsqrt(d2), 1e4*log2e);  rdz = log2e*rcp(dz)
//   via 1/max(a,eps) == min(1/a, 1/eps).  {cx,tm} hoisted per tap-row into per-(o,k)
//   REGISTER tables, k = |dx-RAD| compile-time (R4 lesson: registers, not LDS; R6 lesson:
//   trans issue is cheap -> direct rsq tables, no rolling window).
// Center tap: rsqrt(0)=inf -> tm=BIG; zd==0 -> fma(-0,BIG,cx0)=0; dot==1 -> t=0 -> w=1. Exact.
// (Fusion numerics validated R2-R6: absmax 3.9e-3 vs threshold 2e-2.)

__global__ __launch_bounds__(TX*BDY, 3)
void denoise_kernel(const float* __restrict__ in, float* __restrict__ out) {
    __shared__ float4 sA[LR][LC];   // c0,c1,c2,n0   28224 B
    __shared__ float2 sN[LR][LC];   // n1,n2         14112 B
    __shared__ float  sZ[LR][LC];   // z              7056 B -> 49392 B -> 3 blocks/CU

    const int tx = threadIdx.x;
    const int ty = threadIdx.y;
    const int tid = ty * TX + tx;
    const int x0 = blockIdx.x * TX;
    const int y0 = blockIdx.y * TY;

    // ---- stage tile + halo, normalizing normals on the fly ----
    #pragma unroll
    for (int i = 0; i < (LR * LC + TX * BDY - 1) / (TX * BDY); ++i) {
        int idx = tid + i * (TX * BDY);
        if (idx < LR * LC) {
            int r = idx / LC, c = idx % LC;
            int gx = x0 + c - RAD;
            int gy = y0 + r - RAD;
            float4 a = make_float4(0.f, 0.f, 0.f, 0.f);
            float4 b = make_float4(0.f, 0.f, 0.f, 0.f);
            if ((unsigned)gx < (unsigned)WW && (unsigned)gy < (unsigned)HH) {
                const float4* p = reinterpret_cast<const float4*>(in + ((size_t)gy * WW + gx) * 8);
                a = p[0];
                b = p[1];
            }
            float nn = a.w * a.w + b.x * b.x + b.y * b.y;
            float s = fast_rsq(fmaxf(nn, 1e-20f));
            sA[r][c] = make_float4(a.x, a.y, a.z, a.w * s);
            sN[r][c] = make_float2(b.x * s, b.y * s);
            sZ[r][c] = b.z;
        }
    }
    __syncthreads();

    // ---- per-thread centers: 4 vertically adjacent outputs ----
    float cn0[RPT], cn1[RPT], cn2[RPT], cz[RPT], rdz[RPT];
    #pragma unroll
    for (int o = 0; o < RPT; ++o) {
        int rr = ty * RPT + RAD + o, cc = tx + RAD;
        float4 A = sA[rr][cc];
        float2 N = sN[rr][cc];
        cn0[o] = A.w; cn1[o] = N.x; cn2[o] = N.y; cz[o] = sZ[rr][cc];
        int gy = y0 + ty * RPT + o;
        float dzv = 1.0f;
        if (gy < HH) dzv = in[(((size_t)gy * WW) + (x0 + tx)) * 8 + 7];
        rdz[o] = 1.4426950408889634f * fast_rcp(dzv);   // log2e folded in
    }

    float accx[RPT] = {0.f, 0.f, 0.f, 0.f};
    float accy[RPT] = {0.f, 0.f, 0.f, 0.f};
    float accz[RPT] = {0.f, 0.f, 0.f, 0.f};
    float accw[RPT] = {0.f, 0.f, 0.f, 0.f};

    // ROW_BODY(CHECK): one tap-row. Hoists per-(o,k) {cx,tm} register tables (skipped for
    // invalid o), then the 11x4 unrolled bodies use compile-time k = |dx-RAD|.
    // Steady body: 12 VALU + 1 exp2.
    #define ROW_BODY(CHECK)                                                          \
    {                                                                                \
        float tmv[RPT][RAD + 1], cxv[RPT][RAD + 1];                                  \
        bool  val[RPT];                                                              \
        _Pragma("unroll")                                                            \
        for (int o = 0; o < RPT; ++o) {                                              \
            int dy = r - RAD - o;                                                    \
            val[o] = (dy >= -RAD) && (dy <= RAD);                                    \
            if (!CHECK || val[o]) {                                                  \
                float dy2f = (float)(dy * dy);                                       \
                float bneg = dy2f * -0.18033688011112042f;                           \
                _Pragma("unroll")                                                    \
                for (int k = 0; k <= RAD; ++k) {                                     \
                    const float K2 = (float)(k * k);                                 \
                    cxv[o][k] = bneg + K2 * -0.18033688011112042f;  /* K2-term folds */ \
                    tmv[o][k] = fminf(rdz[o] * fast_rsq(dy2f + K2), 14426.950408889634f); \
                }                                                                    \
            }                                                                        \
        }                                                                            \
        _Pragma("unroll")                                                            \
        for (int dx = 0; dx < 2 * RAD + 1; ++dx) {                                   \
            float4 A  = sA[ty * RPT + r][tx + dx];                                   \
            float2 N  = sN[ty * RPT + r][tx + dx];                                   \
            float  tz = sZ[ty * RPT + r][tx + dx];                                   \
            const int k = (dx < RAD) ? (RAD - dx) : (dx - RAD);                      \
            _Pragma("unroll")                                                        \
            for (int o = 0; o < RPT; ++o) {                                          \
                if (!CHECK || val[o]) {                                              \
                    float dot = fmaf(A.w, cn0[o], fmaf(N.x, cn1[o], N.y * cn2[o]));  \
                    float t   = dot - 1.0f;                                          \
                    float u   = fmaf(t, -92.332482616893665f, 184.66496523378733f);  \
                    float zd  = tz - cz[o];                                          \
                    float e2a = fmaf(-fabsf(zd), tmv[o][k], cxv[o][k]);              \
                    float e2  = fmaf(t, u, e2a);                                     \
                    float w   = fast_exp2(e2);                                       \
                    accx[o] = fmaf(A.x, w, accx[o]);                                 \
                    accy[o] = fmaf(A.y, w, accy[o]);                                 \
                    accz[o] = fmaf(A.z, w, accz[o]);                                 \
                    accw[o] += w;                                                    \
                }                                                                    \
            }                                                                        \
        }                                                                            \
    }

    // ---- boundary rows (some o invalid) ----
    #pragma unroll 1
    for (int r = 0; r < RPT - 1; ++r) ROW_BODY(true)
    // ---- steady rows r in [3,10]: all 4 outputs valid, branch-free ----
    #pragma unroll 1
    for (int r = RPT - 1; r <= 2 * RAD; ++r) ROW_BODY(false)
    // ---- boundary rows ----
    #pragma unroll 1
    for (int r = 2 * RAD + 1; r < 2 * RAD + RPT; ++r) ROW_BODY(true)

    #undef ROW_BODY

    // ---- epilogue ----
    const int xo = x0 + tx;
    #pragma unroll
    for (int o = 0; o < RPT; ++o) {
        int y = y0 + ty * RPT + o;
        if (y < HH) {
            float inv = fast_rcp(accw[o]);
            size_t base = ((size_t)y * WW + xo) * 3;
            out[base + 0] = accx[o] * inv;
            out[base + 1] = accy[o] * inv;
            out[base + 2] = accz[o] * inv;
        }
    }
}

extern "C" void kernel_launch(void* const* d_in, const int* in_sizes, int n_in,
                              void* d_out, int out_size, void* d_ws, size_t ws_size,
                              hipStream_t stream) {
    const float* in = (const float*)d_in[0];
    float* out = (float*)d_out;
    dim3 grid((WW + TX - 1) / TX, (HH + TY - 1) / TY);   // 60 x 34
    dim3 block(TX, BDY);                                  // 256 threads
    hipLaunchKernelGGL(denoise_kernel, grid, block, 0, stream, in, out);
}

// Round 8
// 108.886 us; speedup vs baseline: 1.1510x; 1.0334x over previous
//
#include <hip/hip_runtime.h>
#include <math.h>

#define HH 1080
#define WW 1920
#define RAD 5
#define TX 32
#define TY 24            // 1080/24 = 45 exact; tile+halo LDS fits 4 blocks/CU
#define RPT 3
#define BDY 8
#define LR (TY + 2*RAD)  // 34
#define LC (TX + 2*RAD)  // 42

__device__ __forceinline__ float fast_rcp(float x) {
#if __has_builtin(__builtin_amdgcn_rcpf)
    return __builtin_amdgcn_rcpf(x);
#else
    return 1.0f / x;
#endif
}
__device__ __forceinline__ float fast_rsq(float x) {
#if __has_builtin(__builtin_amdgcn_rsqf)
    return __builtin_amdgcn_rsqf(x);
#else
    return rsqrtf(x);
#endif
}
__device__ __forceinline__ float fast_exp2(float x) {
#if __has_builtin(__builtin_amdgcn_exp2f)
    return __builtin_amdgcn_exp2f(x);
#else
    return exp2f(x);
#endif
}

// Weight: w = exp(-d2/8) * clip(dot,0,1)^128 * exp(-|tz-z| / max(dz*sqrt(d2), 1e-4))
// One exp2; quadratic ln(1+t) ~= t - t^2/2 for the ^128 term, with t = dot-1 FOLDED OUT:
//   e2 = fma(dot, fma(dot, -C/2, 2C), e2a'),  C = 128*log2e
//   e2a' = fma(-|zd|, tm[d2], cx'[d2]),  cx'[d2] = -d2*log2e/8 - 1.5C   (bias absorbed)
//   tm[d2] = min(rdz*rsqrt(d2), 1e4*log2e),  rdz = log2e*rcp(dz)   (1/max(a,e)==min(1/a,1/e))
// Algebraically identical to R7's validated form (absmax 3.9e-3 vs threshold 2e-2):
//   dot=1 (center) -> e2 = 2C - C/2 - 1.5C + cx = cx; zd=0 -> w=1 exact.
//   dot=0 (clip / zero-padded halo mask) -> e2 = cx' <= -277 -> w = 0.
// {cx',tm} hoisted per tap-row into per-(o,k) REGISTER tables, k=|dx-RAD| compile-time
// (R4: registers not LDS; R2: never fully unroll the row loop).

__global__ __launch_bounds__(TX*BDY, 4)
void denoise_kernel(const float* __restrict__ in, float* __restrict__ out) {
    __shared__ float4 sA[LR][LC];   // c0,c1,c2,n0   22848 B
    __shared__ float2 sN[LR][LC];   // n1,n2         11424 B
    __shared__ float  sZ[LR][LC];   // z              5712 B -> 39984 B -> 4 blocks/CU

    const int tx = threadIdx.x;
    const int ty = threadIdx.y;
    const int tid = ty * TX + tx;
    const int x0 = blockIdx.x * TX;
    const int y0 = blockIdx.y * TY;

    // ---- stage tile + halo, normalizing normals on the fly ----
    #pragma unroll
    for (int i = 0; i < (LR * LC + TX * BDY - 1) / (TX * BDY); ++i) {
        int idx = tid + i * (TX * BDY);
        if (idx < LR * LC) {
            int r = idx / LC, c = idx % LC;
            int gx = x0 + c - RAD;
            int gy = y0 + r - RAD;
            float4 a = make_float4(0.f, 0.f, 0.f, 0.f);
            float4 b = make_float4(0.f, 0.f, 0.f, 0.f);
            if ((unsigned)gx < (unsigned)WW && (unsigned)gy < (unsigned)HH) {
                const float4* p = reinterpret_cast<const float4*>(in + ((size_t)gy * WW + gx) * 8);
                a = p[0];
                b = p[1];
            }
            float nn = a.w * a.w + b.x * b.x + b.y * b.y;
            float s = fast_rsq(fmaxf(nn, 1e-20f));
            sA[r][c] = make_float4(a.x, a.y, a.z, a.w * s);
            sN[r][c] = make_float2(b.x * s, b.y * s);
            sZ[r][c] = b.z;
        }
    }
    __syncthreads();

    // ---- per-thread centers: 3 vertically adjacent outputs ----
    float cn0[RPT], cn1[RPT], cn2[RPT], cz[RPT], rdz[RPT];
    #pragma unroll
    for (int o = 0; o < RPT; ++o) {
        int rr = ty * RPT + RAD + o, cc = tx + RAD;
        float4 A = sA[rr][cc];
        float2 N = sN[rr][cc];
        cn0[o] = A.w; cn1[o] = N.x; cn2[o] = N.y; cz[o] = sZ[rr][cc];
        int gy = y0 + ty * RPT + o;       // always < HH (1080 = 45*24 exact)
        float dzv = in[(((size_t)gy * WW) + (x0 + tx)) * 8 + 7];
        rdz[o] = 1.4426950408889634f * fast_rcp(dzv);   // log2e folded in
    }

    float accx[RPT] = {0.f, 0.f, 0.f};
    float accy[RPT] = {0.f, 0.f, 0.f};
    float accz[RPT] = {0.f, 0.f, 0.f};
    float accw[RPT] = {0.f, 0.f, 0.f};

    // ROW_BODY(CHECK): one tap-row. Hoists per-(o,k) {cx',tm} register tables (skipped
    // for invalid o), then 11 x RPT unrolled bodies with compile-time k = |dx-RAD|.
    // Steady body: 11 VALU + 1 exp2.
    #define ROW_BODY(CHECK)                                                          \
    {                                                                                \
        float tmv[RPT][RAD + 1], cxv[RPT][RAD + 1];                                  \
        bool  val[RPT];                                                              \
        _Pragma("unroll")                                                            \
        for (int o = 0; o < RPT; ++o) {                                              \
            int dy = r - RAD - o;                                                    \
            val[o] = (dy >= -RAD) && (dy <= RAD);                                    \
            if (!CHECK || val[o]) {                                                  \
                float dy2f = (float)(dy * dy);                                       \
                float bneg = fmaf(dy2f, -0.18033688011112042f, -276.997447850681f);  \
                _Pragma("unroll")                                                    \
                for (int k = 0; k <= RAD; ++k) {                                     \
                    const float K2 = (float)(k * k);                                 \
                    cxv[o][k] = bneg + K2 * -0.18033688011112042f;                   \
                    tmv[o][k] = fminf(rdz[o] * fast_rsq(dy2f + K2), 14426.950408889634f); \
                }                                                                    \
            }                                                                        \
        }                                                                            \
        _Pragma("unroll")                                                            \
        for (int dx = 0; dx < 2 * RAD + 1; ++dx) {                                   \
            float4 A  = sA[ty * RPT + r][tx + dx];                                   \
            float2 N  = sN[ty * RPT + r][tx + dx];                                   \
            float  tz = sZ[ty * RPT + r][tx + dx];                                   \
            const int k = (dx < RAD) ? (RAD - dx) : (dx - RAD);                      \
            _Pragma("unroll")                                                        \
            for (int o = 0; o < RPT; ++o) {                                          \
                if (!CHECK || val[o]) {                                              \
                    float dot = fmaf(A.w, cn0[o], fmaf(N.x, cn1[o], N.y * cn2[o]));  \
                    float vv  = fmaf(dot, -92.332482616893665f, 369.32993046757466f); \
                    float zd  = tz - cz[o];                                          \
                    float e2a = fmaf(-fabsf(zd), tmv[o][k], cxv[o][k]);              \
                    float e2  = fmaf(dot, vv, e2a);                                  \
                    float w   = fast_exp2(e2);                                       \
                    accx[o] = fmaf(A.x, w, accx[o]);                                 \
                    accy[o] = fmaf(A.y, w, accy[o]);                                 \
                    accz[o] = fmaf(A.z, w, accz[o]);                                 \
                    accw[o] += w;                                                    \
                }                                                                    \
            }                                                                        \
        }                                                                            \
    }

    // ---- boundary rows (some o invalid) ----
    #pragma unroll 1
    for (int r = 0; r < RPT - 1; ++r) ROW_BODY(true)
    // ---- steady rows r in [RPT-1, 2*RAD]: all outputs valid, branch-free ----
    #pragma unroll 1
    for (int r = RPT - 1; r <= 2 * RAD; ++r) ROW_BODY(false)
    // ---- boundary rows ----
    #pragma unroll 1
    for (int r = 2 * RAD + 1; r < 2 * RAD + RPT; ++r) ROW_BODY(true)

    #undef ROW_BODY

    // ---- epilogue ----
    const int xo = x0 + tx;
    #pragma unroll
    for (int o = 0; o < RPT; ++o) {
        int y = y0 + ty * RPT + o;       // always < HH
        float inv = fast_rcp(accw[o]);
        size_t base = ((size_t)y * WW + xo) * 3;
        out[base + 0] = accx[o] * inv;
        out[base + 1] = accy[o] * inv;
        out[base + 2] = accz[o] * inv;
    }
}

extern "C" void kernel_launch(void* const* d_in, const int* in_sizes, int n_in,
                              void* d_out, int out_size, void* d_ws, size_t ws_size,
                              hipStream_t stream) {
    const float* in = (const float*)d_in[0];
    float* out = (float*)d_out;
    dim3 grid((WW + TX - 1) / TX, (HH + TY - 1) / TY);   // 60 x 45
    dim3 block(TX, BDY);                                  // 256 threads
    hipLaunchKernelGGL(denoise_kernel, grid, block, 0, stream, in, out);
}

// Round 9
// 106.764 us; speedup vs baseline: 1.1739x; 1.0199x over previous
//
#include <hip/hip_runtime.h>
#include <math.h>

#define HH 1080
#define WW 1920
#define RAD 5
#define TX 32
#define TY 24            // 1080/24 = 45 exact; tile+halo LDS fits 4 blocks/CU
#define RPT 3
#define BDY 8
#define LR (TY + 2*RAD)  // 34
#define LC (TX + 2*RAD)  // 42

__device__ __forceinline__ float fast_rcp(float x) {
#if __has_builtin(__builtin_amdgcn_rcpf)
    return __builtin_amdgcn_rcpf(x);
#else
    return 1.0f / x;
#endif
}
__device__ __forceinline__ float fast_rsq(float x) {
#if __has_builtin(__builtin_amdgcn_rsqf)
    return __builtin_amdgcn_rsqf(x);
#else
    return rsqrtf(x);
#endif
}
__device__ __forceinline__ float fast_exp2(float x) {
#if __has_builtin(__builtin_amdgcn_exp2f)
    return __builtin_amdgcn_exp2f(x);
#else
    return exp2f(x);
#endif
}

// Weight: w = exp(-d2/8) * clip(dot,0,1)^128 * exp(-|tz-z| / max(dz*sqrt(d2), 1e-4))
// One exp2; quadratic ln(1+t) ~= t - t^2/2 for the ^128 term with t = dot-1 folded out:
//   e2 = fma(dot, fma(dot, -C/2, 2C), e2a'),  C = 128*log2e
//   e2a' = fma(-|zd|, tm[d2], cx'[d2]),  cx'[d2] = -d2*log2e/8 - 1.5C
//   tm[d2] = min(rdz*rsqrt(d2), 1e4*log2e),  rdz = min(log2e*rcp(dz), 1e10)
// tm tables RATIO-CHAIN across tap-rows (R8 pmortem: 18 rsq/row @16cyc was ~12 cyc/body):
//   row r's dy for output o == row r-1's dy for o-1, and tm[o] = rdz[o]*RS(dy), so
//   tmu2 = tmu1*rr2, tmu1 = tmu0*rr1 (rr_o = rdz[o]*rcp(rdz[o-1]), ratios cancel exactly
//   through the chain), only tmu0 computed fresh (6 rsq/row). Clamp AFTER chaining.
//   rdz clamped to 1e10 keeps rr finite-positive -> no inf*0 NaN; rsqrt(0)=inf -> BIG. ok.
// Validated fusion numerics R2-R8: absmax 3.9e-3 vs threshold 2e-2.
// Lessons: R2 never fully unroll the row loop; R4 registers not LDS for tables.

__global__ __launch_bounds__(TX*BDY, 4)
void denoise_kernel(const float* __restrict__ in, float* __restrict__ out) {
    __shared__ float4 sA[LR][LC];   // c0,c1,c2,n0   22848 B
    __shared__ float2 sN[LR][LC];   // n1,n2         11424 B
    __shared__ float  sZ[LR][LC];   // z              5712 B -> 39984 B -> 4 blocks/CU

    const int tx = threadIdx.x;
    const int ty = threadIdx.y;
    const int tid = ty * TX + tx;
    const int x0 = blockIdx.x * TX;
    const int y0 = blockIdx.y * TY;

    // ---- stage tile + halo, normalizing normals on the fly ----
    #pragma unroll
    for (int i = 0; i < (LR * LC + TX * BDY - 1) / (TX * BDY); ++i) {
        int idx = tid + i * (TX * BDY);
        if (idx < LR * LC) {
            int r = idx / LC, c = idx % LC;
            int gx = x0 + c - RAD;
            int gy = y0 + r - RAD;
            float4 a = make_float4(0.f, 0.f, 0.f, 0.f);
            float4 b = make_float4(0.f, 0.f, 0.f, 0.f);
            if ((unsigned)gx < (unsigned)WW && (unsigned)gy < (unsigned)HH) {
                const float4* p = reinterpret_cast<const float4*>(in + ((size_t)gy * WW + gx) * 8);
                a = p[0];
                b = p[1];
            }
            float nn = a.w * a.w + b.x * b.x + b.y * b.y;
            float s = fast_rsq(fmaxf(nn, 1e-20f));
            sA[r][c] = make_float4(a.x, a.y, a.z, a.w * s);
            sN[r][c] = make_float2(b.x * s, b.y * s);
            sZ[r][c] = b.z;
        }
    }
    __syncthreads();

    // ---- per-thread centers: 3 vertically adjacent outputs ----
    float cn0[RPT], cn1[RPT], cn2[RPT], cz[RPT], rdz[RPT];
    #pragma unroll
    for (int o = 0; o < RPT; ++o) {
        int rr = ty * RPT + RAD + o, cc = tx + RAD;
        float4 A = sA[rr][cc];
        float2 N = sN[rr][cc];
        cn0[o] = A.w; cn1[o] = N.x; cn2[o] = N.y; cz[o] = sZ[rr][cc];
        int gy = y0 + ty * RPT + o;       // always < HH (1080 = 45*24 exact)
        float dzv = in[(((size_t)gy * WW) + (x0 + tx)) * 8 + 7];
        rdz[o] = fminf(1.4426950408889634f * fast_rcp(dzv), 1e10f);  // log2e folded; finite
    }
    // chain ratios rr_o = rdz[o]/rdz[o-1]  (finite positive by the clamp above)
    const float rr1 = rdz[1] * fast_rcp(rdz[0]);
    const float rr2 = rdz[2] * fast_rcp(rdz[1]);

    float accx[RPT] = {0.f, 0.f, 0.f};
    float accy[RPT] = {0.f, 0.f, 0.f};
    float accz[RPT] = {0.f, 0.f, 0.f};
    float accw[RPT] = {0.f, 0.f, 0.f};

    // unclamped tm chain state (zero-init: invalid slots chain to 0, gated by val[])
    float tmu0[RAD + 1] = {}, tmu1[RAD + 1] = {}, tmu2[RAD + 1] = {};

    // ROW_BODY(CHECK): one tap-row. Rotate the tm ratio-chain (descending), compute 6
    // fresh rsq for o=0's new dy, clamp into tmv, build cxv, then 11 x RPT unrolled
    // bodies with compile-time k = |dx-RAD|. Steady body: 11 VALU + 1 exp2.
    #define ROW_BODY(CHECK)                                                          \
    {                                                                                \
        _Pragma("unroll")                                                            \
        for (int k = 0; k <= RAD; ++k) tmu2[k] = tmu1[k] * rr2;                      \
        _Pragma("unroll")                                                            \
        for (int k = 0; k <= RAD; ++k) tmu1[k] = tmu0[k] * rr1;                      \
        if (!CHECK || r <= 2 * RAD) {   /* fresh dy only while it can become valid */\
            int dy0 = r - RAD;                                                      \
            float dy0sq = (float)(dy0 * dy0);                                       \
            _Pragma("unroll")                                                       \
            for (int k = 0; k <= RAD; ++k)                                          \
                tmu0[k] = rdz[0] * fast_rsq(dy0sq + (float)(k * k));                \
        }                                                                            \
        float tmv[RPT][RAD + 1], cxv[RPT][RAD + 1];                                  \
        bool  val[RPT];                                                              \
        _Pragma("unroll")                                                            \
        for (int o = 0; o < RPT; ++o) {                                              \
            int dy = r - RAD - o;                                                    \
            val[o] = (dy >= -RAD) && (dy <= RAD);                                    \
            if (!CHECK || val[o]) {                                                  \
                const float* tmu = (o == 0) ? tmu0 : (o == 1) ? tmu1 : tmu2;         \
                float dy2f = (float)(dy * dy);                                       \
                float bneg = fmaf(dy2f, -0.18033688011112042f, -276.997447850681f);  \
                _Pragma("unroll")                                                    \
                for (int k = 0; k <= RAD; ++k) {                                     \
                    cxv[o][k] = bneg + (float)(k * k) * -0.18033688011112042f;       \
                    tmv[o][k] = fminf(tmu[k], 14426.950408889634f);                  \
                }                                                                    \
            }                                                                        \
        }                                                                            \
        _Pragma("unroll")                                                            \
        for (int dx = 0; dx < 2 * RAD + 1; ++dx) {                                   \
            float4 A  = sA[ty * RPT + r][tx + dx];                                   \
            float2 N  = sN[ty * RPT + r][tx + dx];                                   \
            float  tz = sZ[ty * RPT + r][tx + dx];                                   \
            const int k = (dx < RAD) ? (RAD - dx) : (dx - RAD);                      \
            _Pragma("unroll")                                                        \
            for (int o = 0; o < RPT; ++o) {                                          \
                if (!CHECK || val[o]) {                                              \
                    float dot = fmaf(A.w, cn0[o], fmaf(N.x, cn1[o], N.y * cn2[o]));  \
                    float vv  = fmaf(dot, -92.332482616893665f, 369.32993046757466f); \
                    float zd  = tz - cz[o];                                          \
                    float e2a = fmaf(-fabsf(zd), tmv[o][k], cxv[o][k]);              \
                    float e2  = fmaf(dot, vv, e2a);                                  \
                    float w   = fast_exp2(e2);                                       \
                    accx[o] = fmaf(A.x, w, accx[o]);                                 \
                    accy[o] = fmaf(A.y, w, accy[o]);                                 \
                    accz[o] = fmaf(A.z, w, accz[o]);                                 \
                    accw[o] += w;                                                    \
                }                                                                    \
            }                                                                        \
        }                                                                            \
    }

    // ---- boundary rows (some o invalid) ----
    #pragma unroll 1
    for (int r = 0; r < RPT - 1; ++r) ROW_BODY(true)
    // ---- steady rows r in [RPT-1, 2*RAD]: all outputs valid, branch-free ----
    #pragma unroll 1
    for (int r = RPT - 1; r <= 2 * RAD; ++r) ROW_BODY(false)
    // ---- boundary rows ----
    #pragma unroll 1
    for (int r = 2 * RAD + 1; r < 2 * RAD + RPT; ++r) ROW_BODY(true)

    #undef ROW_BODY

    // ---- epilogue ----
    const int xo = x0 + tx;
    #pragma unroll
    for (int o = 0; o < RPT; ++o) {
        int y = y0 + ty * RPT + o;       // always < HH
        float inv = fast_rcp(accw[o]);
        size_t base = ((size_t)y * WW + xo) * 3;
        out[base + 0] = accx[o] * inv;
        out[base + 1] = accy[o] * inv;
        out[base + 2] = accz[o] * inv;
    }
}

extern "C" void kernel_launch(void* const* d_in, const int* in_sizes, int n_in,
                              void* d_out, int out_size, void* d_ws, size_t ws_size,
                              hipStream_t stream) {
    const float* in = (const float*)d_in[0];
    float* out = (float*)d_out;
    dim3 grid((WW + TX - 1) / TX, (HH + TY - 1) / TY);   // 60 x 45
    dim3 block(TX, BDY);                                  // 256 threads
    hipLaunchKernelGGL(denoise_kernel, grid, block, 0, stream, in, out);
}

// Round 10
// 106.365 us; speedup vs baseline: 1.1783x; 1.0037x over previous
//
#include <hip/hip_runtime.h>
#include <math.h>

#define HH 1080
#define WW 1920
#define RAD 5
#define TX 32
#define TY 24            // 1080/24 = 45 exact; tile+halo LDS fits 4 blocks/CU
#define RPT 3
#define BDY 8
#define LR (TY + 2*RAD)  // 34
#define LC (TX + 2*RAD)  // 42

__device__ __forceinline__ float fast_rcp(float x) {
#if __has_builtin(__builtin_amdgcn_rcpf)
    return __builtin_amdgcn_rcpf(x);
#else
    return 1.0f / x;
#endif
}
__device__ __forceinline__ float fast_rsq(float x) {
#if __has_builtin(__builtin_amdgcn_rsqf)
    return __builtin_amdgcn_rsqf(x);
#else
    return rsqrtf(x);
#endif
}
__device__ __forceinline__ float fast_exp2(float x) {
#if __has_builtin(__builtin_amdgcn_exp2f)
    return __builtin_amdgcn_exp2f(x);
#else
    return exp2f(x);
#endif
}

// Weight: w = exp(-d2/8) * clip(dot,0,1)^128 * exp(-|tz-z| / max(dz*sqrt(d2), 1e-4))
// One exp2; quadratic ln(1+t) ~= t - t^2/2 for the ^128 term with t = dot-1 folded out:
//   e2 = fma(dot, fma(dot, -C/2, 2C), e2a'),  C = 128*log2e
//   e2a' = fma(-|zd|, tm[d2], cx'[d2]),  cx'[d2] = -d2*log2e/8 - 1.5C
//   tm[d2] = min(rdz*rsqrt(d2), 1e4*log2e),  rdz = min(log2e*rcp(dz), 1e10)
// tm tables RATIO-CHAIN across tap-rows: row r's dy for output o == row r-1's dy for
// o-1, and tm[o] = rdz[o]*RS(dy), so tmu2 = tmu1*rr2, tmu1 = tmu0*rr1 (ratios cancel
// exactly), only tmu0 computed fresh (6 rsq/row). Clamp AFTER chaining.
// R9 lesson (rule #20): select chain slots BY VALUE with compile-time (o,k) —
// a pointer-select (const float* tmu = o==0?tmu0:...) takes the arrays' address,
// demotes them to scratch (WRITE_SIZE 24->46MB), and stalls the VALU.
// Validated fusion numerics R2-R9: absmax 3.9e-3 vs threshold 2e-2.
// Other lessons: R2 never fully unroll the row loop; R4 registers not LDS for tables.

__global__ __launch_bounds__(TX*BDY, 4)
void denoise_kernel(const float* __restrict__ in, float* __restrict__ out) {
    __shared__ float4 sA[LR][LC];   // c0,c1,c2,n0   22848 B
    __shared__ float2 sN[LR][LC];   // n1,n2         11424 B
    __shared__ float  sZ[LR][LC];   // z              5712 B -> 39984 B -> 4 blocks/CU

    const int tx = threadIdx.x;
    const int ty = threadIdx.y;
    const int tid = ty * TX + tx;
    const int x0 = blockIdx.x * TX;
    const int y0 = blockIdx.y * TY;

    // ---- stage tile + halo, normalizing normals on the fly ----
    #pragma unroll
    for (int i = 0; i < (LR * LC + TX * BDY - 1) / (TX * BDY); ++i) {
        int idx = tid + i * (TX * BDY);
        if (idx < LR * LC) {
            int r = idx / LC, c = idx % LC;
            int gx = x0 + c - RAD;
            int gy = y0 + r - RAD;
            float4 a = make_float4(0.f, 0.f, 0.f, 0.f);
            float4 b = make_float4(0.f, 0.f, 0.f, 0.f);
            if ((unsigned)gx < (unsigned)WW && (unsigned)gy < (unsigned)HH) {
                const float4* p = reinterpret_cast<const float4*>(in + ((size_t)gy * WW + gx) * 8);
                a = p[0];
                b = p[1];
            }
            float nn = a.w * a.w + b.x * b.x + b.y * b.y;
            float s = fast_rsq(fmaxf(nn, 1e-20f));
            sA[r][c] = make_float4(a.x, a.y, a.z, a.w * s);
            sN[r][c] = make_float2(b.x * s, b.y * s);
            sZ[r][c] = b.z;
        }
    }
    __syncthreads();

    // ---- per-thread centers: 3 vertically adjacent outputs ----
    float cn0[RPT], cn1[RPT], cn2[RPT], cz[RPT], rdz[RPT];
    #pragma unroll
    for (int o = 0; o < RPT; ++o) {
        int rr = ty * RPT + RAD + o, cc = tx + RAD;
        float4 A = sA[rr][cc];
        float2 N = sN[rr][cc];
        cn0[o] = A.w; cn1[o] = N.x; cn2[o] = N.y; cz[o] = sZ[rr][cc];
        int gy = y0 + ty * RPT + o;       // always < HH (1080 = 45*24 exact)
        float dzv = in[(((size_t)gy * WW) + (x0 + tx)) * 8 + 7];
        rdz[o] = fminf(1.4426950408889634f * fast_rcp(dzv), 1e10f);  // log2e folded; finite
    }
    // chain ratios rr_o = rdz[o]/rdz[o-1]  (finite positive by the clamp above)
    const float rr1 = rdz[1] * fast_rcp(rdz[0]);
    const float rr2 = rdz[2] * fast_rcp(rdz[1]);

    float accx[RPT] = {0.f, 0.f, 0.f};
    float accy[RPT] = {0.f, 0.f, 0.f};
    float accz[RPT] = {0.f, 0.f, 0.f};
    float accw[RPT] = {0.f, 0.f, 0.f};

    // unclamped tm chain state (zero-init: invalid slots chain to 0, gated by val[])
    float tmu0[RAD + 1] = {}, tmu1[RAD + 1] = {}, tmu2[RAD + 1] = {};

    // ROW_BODY(CHECK): one tap-row. Rotate the tm ratio-chain (descending), compute 6
    // fresh rsq for o=0's new dy, clamp into tmv via VALUE-select (no address taken),
    // build cxv, then 11 x RPT unrolled bodies with compile-time k = |dx-RAD|.
    // Steady body: 11 VALU + 1 exp2.
    #define ROW_BODY(CHECK)                                                          \
    {                                                                                \
        _Pragma("unroll")                                                            \
        for (int k = 0; k <= RAD; ++k) tmu2[k] = tmu1[k] * rr2;                      \
        _Pragma("unroll")                                                            \
        for (int k = 0; k <= RAD; ++k) tmu1[k] = tmu0[k] * rr1;                      \
        if (!CHECK || r <= 2 * RAD) {   /* fresh dy only while it can become valid */\
            int dy0 = r - RAD;                                                      \
            float dy0sq = (float)(dy0 * dy0);                                       \
            _Pragma("unroll")                                                       \
            for (int k = 0; k <= RAD; ++k)                                          \
                tmu0[k] = rdz[0] * fast_rsq(dy0sq + (float)(k * k));                \
        }                                                                            \
        float tmv[RPT][RAD + 1], cxv[RPT][RAD + 1];                                  \
        bool  val[RPT];                                                              \
        _Pragma("unroll")                                                            \
        for (int o = 0; o < RPT; ++o) {                                              \
            int dy = r - RAD - o;                                                    \
            val[o] = (dy >= -RAD) && (dy <= RAD);                                    \
            if (!CHECK || val[o]) {                                                  \
                float dy2f = (float)(dy * dy);                                       \
                float bneg = fmaf(dy2f, -0.18033688011112042f, -276.997447850681f);  \
                _Pragma("unroll")                                                    \
                for (int k = 0; k <= RAD; ++k) {                                     \
                    float tmuk = (o == 0) ? tmu0[k] : (o == 1) ? tmu1[k] : tmu2[k];  \
                    cxv[o][k] = bneg + (float)(k * k) * -0.18033688011112042f;       \
                    tmv[o][k] = fminf(tmuk, 14426.950408889634f);                    \
                }                                                                    \
            }                                                                        \
        }                                                                            \
        _Pragma("unroll")                                                            \
        for (int dx = 0; dx < 2 * RAD + 1; ++dx) {                                   \
            float4 A  = sA[ty * RPT + r][tx + dx];                                   \
            float2 N  = sN[ty * RPT + r][tx + dx];                                   \
            float  tz = sZ[ty * RPT + r][tx + dx];                                   \
            const int k = (dx < RAD) ? (RAD - dx) : (dx - RAD);                      \
            _Pragma("unroll")                                                        \
            for (int o = 0; o < RPT; ++o) {                                          \
                if (!CHECK || val[o]) {                                              \
                    float dot = fmaf(A.w, cn0[o], fmaf(N.x, cn1[o], N.y * cn2[o]));  \
                    float vv  = fmaf(dot, -92.332482616893665f, 369.32993046757466f); \
                    float zd  = tz - cz[o];                                          \
                    float e2a = fmaf(-fabsf(zd), tmv[o][k], cxv[o][k]);              \
                    float e2  = fmaf(dot, vv, e2a);                                  \
                    float w   = fast_exp2(e2);                                       \
                    accx[o] = fmaf(A.x, w, accx[o]);                                 \
                    accy[o] = fmaf(A.y, w, accy[o]);                                 \
                    accz[o] = fmaf(A.z, w, accz[o]);                                 \
                    accw[o] += w;                                                    \
                }                                                                    \
            }                                                                        \
        }                                                                            \
    }

    // ---- boundary rows (some o invalid) ----
    #pragma unroll 1
    for (int r = 0; r < RPT - 1; ++r) ROW_BODY(true)
    // ---- steady rows r in [RPT-1, 2*RAD]: all outputs valid, branch-free ----
    #pragma unroll 1
    for (int r = RPT - 1; r <= 2 * RAD; ++r) ROW_BODY(false)
    // ---- boundary rows ----
    #pragma unroll 1
    for (int r = 2 * RAD + 1; r < 2 * RAD + RPT; ++r) ROW_BODY(true)

    #undef ROW_BODY

    // ---- epilogue ----
    const int xo = x0 + tx;
    #pragma unroll
    for (int o = 0; o < RPT; ++o) {
        int y = y0 + ty * RPT + o;       // always < HH
        float inv = fast_rcp(accw[o]);
        size_t base = ((size_t)y * WW + xo) * 3;
        out[base + 0] = accx[o] * inv;
        out[base + 1] = accy[o] * inv;
        out[base + 2] = accz[o] * inv;
    }
}

extern "C" void kernel_launch(void* const* d_in, const int* in_sizes, int n_in,
                              void* d_out, int out_size, void* d_ws, size_t ws_size,
                              hipStream_t stream) {
    const float* in = (const float*)d_in[0];
    float* out = (float*)d_out;
    dim3 grid((WW + TX - 1) / TX, (HH + TY - 1) / TY);   // 60 x 45
    dim3 block(TX, BDY);                                  // 256 threads
    hipLaunchKernelGGL(denoise_kernel, grid, block, 0, stream, in, out);
}